// Round 3
// baseline (234.398 us; speedup 1.0000x reference)
//
#include <hip/hip_runtime.h>
#include <hip/hip_bf16.h>

// Attention: xq/xk/xv [2,2048,768] f32, W* [768,768] f32 ([out,in]), bp [768] f32.
// Pipeline: fused cast->bf16, fused QKV NT-GEMM (scale*log2e folded into Q; V
// computed TRANSPOSED via swapped operands: V^T = Wv Xv^T, coalesced writes),
// flash attention (max-free softmax with exp2, double-buffered K/V staging),
// output NT-GEMM + bias (f32 out).

#define NSEQ 2048
#define CDIM 768
#define NH   12
#define HD   64
#define MTOT 4096            // B*NSEQ
#define XEL  (MTOT*CDIM)     // 3145728
#define WEL  (CDIM*CDIM)     // 589824
#define X8   (XEL/8)         // 393216
#define W8   (WEL/8)         // 73728
#define PSTR 72              // P row stride (shorts): 144B, 16B-aligned, bank-friendly
#define QSCALE 0.18033688011112042f   // 0.125 * log2(e); scores consumed by exp2

typedef __attribute__((ext_vector_type(8))) short bf16x8;
typedef __attribute__((ext_vector_type(4))) float floatx4;
typedef __attribute__((ext_vector_type(8))) unsigned short ushort8;

static __device__ __forceinline__ unsigned short f2bf(float f) {
  union { float f; unsigned int u; } v; v.f = f;
  return (unsigned short)((v.u + 0x7FFFu + ((v.u >> 16) & 1u)) >> 16);
}

static __device__ __forceinline__ void lds16(const void* g, void* l) {
  __builtin_amdgcn_global_load_lds(
      (const __attribute__((address_space(1))) unsigned int*)g,
      (__attribute__((address_space(3))) unsigned int*)l, 16, 0, 0);
}

// ---------------- fused cast f32 -> bf16 (all 7 tensors, one launch) ----------
__global__ __launch_bounds__(256) void cast_all(
    const float* __restrict__ xq, const float* __restrict__ xk,
    const float* __restrict__ xv, const float* __restrict__ wq,
    const float* __restrict__ wk, const float* __restrict__ wv,
    const float* __restrict__ wp,
    unsigned short* __restrict__ Xq, unsigned short* __restrict__ Xk,
    unsigned short* __restrict__ Xv, unsigned short* __restrict__ Wq,
    unsigned short* __restrict__ Wk, unsigned short* __restrict__ Wv,
    unsigned short* __restrict__ Wp) {
  int i = blockIdx.x * 256 + threadIdx.x;
  const float* s; unsigned short* d; int off;
  if (i < 3 * X8) {
    int t = i / X8; off = i - t * X8;
    s = (t == 0) ? xq : (t == 1) ? xk : xv;
    d = (t == 0) ? Xq : (t == 1) ? Xk : Xv;
  } else {
    int j = i - 3 * X8; int t = j / W8; off = j - t * W8;
    s = (t == 0) ? wq : (t == 1) ? wk : (t == 2) ? wv : wp;
    d = (t == 0) ? Wq : (t == 1) ? Wk : (t == 2) ? Wv : Wp;
  }
  const float4* sp = (const float4*)s + (size_t)off * 2;
  float4 a = sp[0], b = sp[1];
  ushort8 o;
  o[0] = f2bf(a.x); o[1] = f2bf(a.y); o[2] = f2bf(a.z); o[3] = f2bf(a.w);
  o[4] = f2bf(b.x); o[5] = f2bf(b.y); o[6] = f2bf(b.z); o[7] = f2bf(b.w);
  *(ushort8*)(d + (size_t)off * 8) = o;
}

// ---------------- fused QKV NT-GEMM ----------------
// z=0: Q = Xq Wq^T, scaled by QSCALE, out [B,H,N,D]
// z=1: K = Xk Wk^T, out [B,H,N,D]
// z=2: V^T = Wv Xv^T (operands swapped so writes to Vt [B,H,D,N] are coalesced)
__global__ __launch_bounds__(256) void gemm_qkv(
    const unsigned short* __restrict__ Xq, const unsigned short* __restrict__ Xk,
    const unsigned short* __restrict__ Xv, const unsigned short* __restrict__ Wq,
    const unsigned short* __restrict__ Wk, const unsigned short* __restrict__ Wv,
    unsigned short* __restrict__ Qo, unsigned short* __restrict__ Ko,
    unsigned short* __restrict__ Vo) {
  int z = blockIdx.z;
  const unsigned short* A; const unsigned short* B; int m0, n0;
  if (z == 0)      { A = Xq; B = Wq; m0 = blockIdx.y * 128; n0 = blockIdx.x * 128; }
  else if (z == 1) { A = Xk; B = Wk; m0 = blockIdx.y * 128; n0 = blockIdx.x * 128; }
  else             { A = Wv; B = Xv; m0 = blockIdx.x * 128; n0 = blockIdx.y * 128; }
  __shared__ __align__(16) unsigned short As[128 * 64];
  __shared__ __align__(16) unsigned short Bs[128 * 64];
  int tid = threadIdx.x, lane = tid & 63, wave = tid >> 6;
  int quad = lane >> 4, l15 = lane & 15;
  int lrow = lane >> 3, lcol = lane & 7;
  int wm = (wave >> 1) * 64, wn = (wave & 1) * 64;
  floatx4 acc[4][4];
#pragma unroll
  for (int i = 0; i < 4; i++)
#pragma unroll
    for (int j = 0; j < 4; j++) acc[i][j] = (floatx4){0.f, 0.f, 0.f, 0.f};

  for (int k0 = 0; k0 < CDIM; k0 += 64) {
    const unsigned short* ga = A + (size_t)(m0 + wave * 32 + lrow) * CDIM + k0 + lcol * 8;
    const unsigned short* gb = B + (size_t)(n0 + wave * 32 + lrow) * CDIM + k0 + lcol * 8;
#pragma unroll
    for (int i = 0; i < 4; i++) {
      lds16(ga + (size_t)i * 8 * CDIM, &As[(wave * 32 + i * 8) * 64]);
      lds16(gb + (size_t)i * 8 * CDIM, &Bs[(wave * 32 + i * 8) * 64]);
    }
    __syncthreads();
#pragma unroll
    for (int ks = 0; ks < 2; ks++) {
      bf16x8 af[4], bfr[4];
#pragma unroll
      for (int i = 0; i < 4; i++)
        af[i] = *(const bf16x8*)&As[(wm + i * 16 + l15) * 64 + ks * 32 + quad * 8];
#pragma unroll
      for (int i = 0; i < 4; i++)
        bfr[i] = *(const bf16x8*)&Bs[(wn + i * 16 + l15) * 64 + ks * 32 + quad * 8];
#pragma unroll
      for (int mi = 0; mi < 4; mi++)
#pragma unroll
        for (int ni = 0; ni < 4; ni++)
          acc[mi][ni] = __builtin_amdgcn_mfma_f32_16x16x32_bf16(
              af[mi], bfr[ni], acc[mi][ni], 0, 0, 0);
    }
    __syncthreads();
  }
  // epilogue: C/D layout row=(quad*4+r), col=l15
#pragma unroll
  for (int mi = 0; mi < 4; mi++) {
#pragma unroll
    for (int ni = 0; ni < 4; ni++) {
#pragma unroll
      for (int r = 0; r < 4; r++) {
        int grow = m0 + wm + mi * 16 + quad * 4 + r;
        int gcol = n0 + wn + ni * 16 + l15;
        float v = acc[mi][ni][r];
        if (z == 0) {
          int b = grow >> 11, nq = grow & 2047, h = gcol >> 6, d = gcol & 63;
          Qo[((size_t)(b * NH + h) * NSEQ + nq) * HD + d] = f2bf(v * QSCALE);
        } else if (z == 1) {
          int b = grow >> 11, nq = grow & 2047, h = gcol >> 6, d = gcol & 63;
          Ko[((size_t)(b * NH + h) * NSEQ + nq) * HD + d] = f2bf(v);
        } else {
          // grow = o (0..767), gcol = global m (0..4095); coalesced over l15
          int b = gcol >> 11, nq = gcol & 2047;
          Vo[((size_t)b * CDIM + grow) * NSEQ + nq] = f2bf(v);
        }
      }
    }
  }
}

// ---------------- flash attention (max-free softmax, dbuf staging) ----------
// Q,K: [24][2048][64] bf16 (Q pre-scaled by QSCALE); Vt: [24][64][2048] bf16.
// ctx: [4096][768] bf16. grid=(32 qtiles, 24 bh), 128 thr (2 waves x 32 qrows).
// K/V LDS XOR-swizzled (chunk ^= row&7) on the global side of global_load_lds.
// Double-buffered: prefetch tile t+1 before computing t; one barrier per tile
// (vmcnt(0) at the barrier is ~free: loads had the whole compute phase to land).
__global__ __launch_bounds__(128) void attn_kernel(
    const unsigned short* __restrict__ Q, const unsigned short* __restrict__ K,
    const unsigned short* __restrict__ Vt, unsigned short* __restrict__ ctx) {
  int qt = blockIdx.x, bh = blockIdx.y;
  int tid = threadIdx.x, lane = tid & 63, wave = tid >> 6;
  int quad = lane >> 4, l15 = lane & 15;
  __shared__ __align__(16) unsigned short Ks[2][64 * 64];
  __shared__ __align__(16) unsigned short Vs[2][64 * 64];
  __shared__ __align__(16) unsigned short Ps[2][32 * PSTR];

  const unsigned short* Qg = Q + ((size_t)bh * NSEQ + qt * 64 + wave * 32) * HD;
  const unsigned short* Kg = K + (size_t)bh * NSEQ * HD;
  const unsigned short* Vg = Vt + (size_t)bh * HD * NSEQ;

  // Q fragments in registers (A-layout): qf[qi][ks]
  bf16x8 qf[2][2];
#pragma unroll
  for (int qi = 0; qi < 2; qi++)
#pragma unroll
    for (int ks = 0; ks < 2; ks++)
      qf[qi][ks] = *(const bf16x8*)(Qg + (qi * 16 + l15) * HD + ks * 32 + quad * 8);

  // staging offsets (loop-invariant): thread covers 4 chunks of each tile
  int koff[4], voff[4], ldst[4];
#pragma unroll
  for (int i = 0; i < 4; i++) {
    int idx = i * 128 + tid;
    int R = idx >> 3, c = (idx & 7) ^ (R & 7);
    koff[i] = R * HD + c * 8;
    voff[i] = R * NSEQ + c * 8;
    ldst[i] = idx * 8;
  }
  // swizzled fragment offsets (shorts) for K and V tiles
  int fragoff[8];
#pragma unroll
  for (int t16 = 0; t16 < 4; t16++)
#pragma unroll
    for (int ks = 0; ks < 2; ks++) {
      int R = t16 * 16 + l15, c = ks * 4 + quad;
      fragoff[t16 * 2 + ks] = R * 64 + (c ^ (R & 7)) * 8;
    }
  unsigned short* Pw = &Ps[wave][0];
  int psrd[2][2];
#pragma unroll
  for (int qi = 0; qi < 2; qi++)
#pragma unroll
    for (int ks = 0; ks < 2; ks++)
      psrd[qi][ks] = (qi * 16 + l15) * PSTR + ks * 32 + quad * 8;

  float l[2][4];
  floatx4 o[2][4];
#pragma unroll
  for (int qi = 0; qi < 2; qi++)
#pragma unroll
    for (int r = 0; r < 4; r++) l[qi][r] = 0.f;
#pragma unroll
  for (int qi = 0; qi < 2; qi++)
#pragma unroll
    for (int dt = 0; dt < 4; dt++) o[qi][dt] = (floatx4){0.f, 0.f, 0.f, 0.f};

  // prologue: stage tile 0 into buffer 0
#pragma unroll
  for (int i = 0; i < 4; i++) {
    lds16(Kg + koff[i], &Ks[0][ldst[i]]);
    lds16(Vg + voff[i], &Vs[0][ldst[i]]);
  }
  __syncthreads();

  for (int t = 0; t < 32; t++) {
    int cur = t & 1;
    if (t < 31) {
      const unsigned short* Kn = Kg + (size_t)(t + 1) * 64 * HD;
      const unsigned short* Vn = Vg + (size_t)(t + 1) * 64;
#pragma unroll
      for (int i = 0; i < 4; i++) {
        lds16(Kn + koff[i], &Ks[cur ^ 1][ldst[i]]);
        lds16(Vn + voff[i], &Vs[cur ^ 1][ldst[i]]);
      }
    }
    // S = Q K^T : s[qi][nt], rows q=quad*4+r, cols kv=nt*16+l15
    bf16x8 kf[4][2];
#pragma unroll
    for (int nt = 0; nt < 4; nt++)
#pragma unroll
      for (int ks = 0; ks < 2; ks++)
        kf[nt][ks] = *(const bf16x8*)&Ks[cur][fragoff[nt * 2 + ks]];
    floatx4 s[2][4];
#pragma unroll
    for (int qi = 0; qi < 2; qi++)
#pragma unroll
      for (int nt = 0; nt < 4; nt++) {
        floatx4 z = (floatx4){0.f, 0.f, 0.f, 0.f};
        z = __builtin_amdgcn_mfma_f32_16x16x32_bf16(qf[qi][0], kf[nt][0], z, 0, 0, 0);
        s[qi][nt] = __builtin_amdgcn_mfma_f32_16x16x32_bf16(qf[qi][1], kf[nt][1], z, 0, 0, 0);
      }
    // max-free softmax: p = exp2(s) (log2e folded into Q); P -> LDS (A-layout)
#pragma unroll
    for (int qi = 0; qi < 2; qi++)
#pragma unroll
      for (int nt = 0; nt < 4; nt++)
#pragma unroll
        for (int r = 0; r < 4; r++) {
          float p = __builtin_exp2f(s[qi][nt][r]);
          l[qi][r] += p;
          Pw[(qi * 16 + quad * 4 + r) * PSTR + nt * 16 + l15] = f2bf(p);
        }
    // O += P V  (wave-private P; compiler inserts lgkmcnt waits)
    bf16x8 vf[4][2];
#pragma unroll
    for (int dt = 0; dt < 4; dt++)
#pragma unroll
      for (int ks = 0; ks < 2; ks++)
        vf[dt][ks] = *(const bf16x8*)&Vs[cur][fragoff[dt * 2 + ks]];
#pragma unroll
    for (int qi = 0; qi < 2; qi++)
#pragma unroll
      for (int ks = 0; ks < 2; ks++) {
        bf16x8 af = *(const bf16x8*)&Pw[psrd[qi][ks]];
#pragma unroll
        for (int dt = 0; dt < 4; dt++)
          o[qi][dt] = __builtin_amdgcn_mfma_f32_16x16x32_bf16(af, vf[dt][ks], o[qi][dt], 0, 0, 0);
      }
    __syncthreads();
  }
  // reduce l over the 16 lanes sharing a row (low 4 lane bits)
#pragma unroll
  for (int qi = 0; qi < 2; qi++)
#pragma unroll
    for (int r = 0; r < 4; r++) {
#pragma unroll
      for (int off = 1; off < 16; off <<= 1)
        l[qi][r] += __shfl_xor(l[qi][r], off, 64);
    }
  int b = bh / NH, h = bh - b * NH;
#pragma unroll
  for (int qi = 0; qi < 2; qi++)
#pragma unroll
    for (int r = 0; r < 4; r++) {
      float inv = 1.f / l[qi][r];
      int qrow = qt * 64 + wave * 32 + qi * 16 + quad * 4 + r;
      size_t grow = (size_t)(b * NSEQ + qrow) * CDIM;
#pragma unroll
      for (int dt = 0; dt < 4; dt++)
        ctx[grow + h * HD + dt * 16 + l15] = f2bf(o[qi][dt][r] * inv);
    }
}

// ---------------- output NT-GEMM + bias, f32 out ----------------
__global__ __launch_bounds__(256) void gemm_out(
    const unsigned short* __restrict__ A, const unsigned short* __restrict__ B,
    const float* __restrict__ bias, float* __restrict__ out) {
  int m0 = blockIdx.y * 128, n0 = blockIdx.x * 128;
  __shared__ __align__(16) unsigned short As[128 * 64];
  __shared__ __align__(16) unsigned short Bs[128 * 64];
  int tid = threadIdx.x, lane = tid & 63, wave = tid >> 6;
  int quad = lane >> 4, l15 = lane & 15;
  int lrow = lane >> 3, lcol = lane & 7;
  int wm = (wave >> 1) * 64, wn = (wave & 1) * 64;
  floatx4 acc[4][4];
#pragma unroll
  for (int i = 0; i < 4; i++)
#pragma unroll
    for (int j = 0; j < 4; j++) acc[i][j] = (floatx4){0.f, 0.f, 0.f, 0.f};

  for (int k0 = 0; k0 < CDIM; k0 += 64) {
    const unsigned short* ga = A + (size_t)(m0 + wave * 32 + lrow) * CDIM + k0 + lcol * 8;
    const unsigned short* gb = B + (size_t)(n0 + wave * 32 + lrow) * CDIM + k0 + lcol * 8;
#pragma unroll
    for (int i = 0; i < 4; i++) {
      lds16(ga + (size_t)i * 8 * CDIM, &As[(wave * 32 + i * 8) * 64]);
      lds16(gb + (size_t)i * 8 * CDIM, &Bs[(wave * 32 + i * 8) * 64]);
    }
    __syncthreads();
#pragma unroll
    for (int ks = 0; ks < 2; ks++) {
      bf16x8 af[4], bfr[4];
#pragma unroll
      for (int i = 0; i < 4; i++)
        af[i] = *(const bf16x8*)&As[(wm + i * 16 + l15) * 64 + ks * 32 + quad * 8];
#pragma unroll
      for (int i = 0; i < 4; i++)
        bfr[i] = *(const bf16x8*)&Bs[(wn + i * 16 + l15) * 64 + ks * 32 + quad * 8];
#pragma unroll
      for (int mi = 0; mi < 4; mi++)
#pragma unroll
        for (int ni = 0; ni < 4; ni++)
          acc[mi][ni] = __builtin_amdgcn_mfma_f32_16x16x32_bf16(
              af[mi], bfr[ni], acc[mi][ni], 0, 0, 0);
    }
    __syncthreads();
  }
  float bv[4];
#pragma unroll
  for (int ni = 0; ni < 4; ni++) bv[ni] = bias[n0 + wn + ni * 16 + l15];
#pragma unroll
  for (int mi = 0; mi < 4; mi++)
#pragma unroll
    for (int ni = 0; ni < 4; ni++)
#pragma unroll
      for (int r = 0; r < 4; r++) {
        int grow = m0 + wm + mi * 16 + quad * 4 + r;
        int gcol = n0 + wn + ni * 16 + l15;
        out[(size_t)grow * CDIM + gcol] = acc[mi][ni][r] + bv[ni];
      }
}

extern "C" void kernel_launch(void* const* d_in, const int* in_sizes, int n_in,
                              void* d_out, int out_size, void* d_ws, size_t ws_size,
                              hipStream_t stream) {
  const float* xq = (const float*)d_in[0];
  const float* xk = (const float*)d_in[1];
  const float* xv = (const float*)d_in[2];
  const float* wq = (const float*)d_in[3];
  const float* wk = (const float*)d_in[4];
  const float* wv = (const float*)d_in[5];
  const float* wp = (const float*)d_in[6];
  const float* bp = (const float*)d_in[7];
  float* out = (float*)d_out;

  char* p = (char*)d_ws;
  unsigned short* Xq = (unsigned short*)p; p += (size_t)XEL * 2;
  unsigned short* Xk = (unsigned short*)p; p += (size_t)XEL * 2;
  unsigned short* Xv = (unsigned short*)p; p += (size_t)XEL * 2;
  unsigned short* Wq = (unsigned short*)p; p += (size_t)WEL * 2;
  unsigned short* Wk = (unsigned short*)p; p += (size_t)WEL * 2;
  unsigned short* Wv = (unsigned short*)p; p += (size_t)WEL * 2;
  unsigned short* Wp = (unsigned short*)p; p += (size_t)WEL * 2;
  unsigned short* Qb = (unsigned short*)p; p += (size_t)XEL * 2;
  unsigned short* Kb = (unsigned short*)p; p += (size_t)XEL * 2;
  unsigned short* Vb = (unsigned short*)p; p += (size_t)XEL * 2;
  unsigned short* Cx = (unsigned short*)p; p += (size_t)XEL * 2;

  cast_all<<<(3 * X8 + 4 * W8) / 256, 256, 0, stream>>>(
      xq, xk, xv, wq, wk, wv, wp, Xq, Xk, Xv, Wq, Wk, Wv, Wp);

  gemm_qkv<<<dim3(CDIM / 128, MTOT / 128, 3), 256, 0, stream>>>(
      Xq, Xk, Xv, Wq, Wk, Wv, Qb, Kb, Vb);

  attn_kernel<<<dim3(NSEQ / 64, 2 * NH), 128, 0, stream>>>(Qb, Kb, Vb, Cx);

  gemm_out<<<dim3(CDIM / 128, MTOT / 128), 256, 0, stream>>>(Cx, Wp, bp, out);
}

// Round 4
// 215.798 us; speedup vs baseline: 1.0862x; 1.0862x over previous
//
#include <hip/hip_runtime.h>
#include <hip/hip_bf16.h>

// Attention: xq/xk/xv [2,2048,768] f32, W* [768,768] f32 ([out,in]), bp [768] f32.
// Pipeline: fused cast->bf16, fused QKV NT-GEMM (scale*log2e folded into Q; V
// computed TRANSPOSED via swapped operands), flash attention computing S^T=K*Q^T
// (max-free softmax via exp2; P written as packed b64 in [q][kv] layout),
// output NT-GEMM + bias (f32 out). All LDS tiles XOR-swizzled (chunk ^= row&7).

#define NSEQ 2048
#define CDIM 768
#define NH   12
#define HD   64
#define MTOT 4096            // B*NSEQ
#define XEL  (MTOT*CDIM)     // 3145728
#define WEL  (CDIM*CDIM)     // 589824
#define X8   (XEL/8)         // 393216
#define W8   (WEL/8)         // 73728
#define PSTR 72              // P row stride (shorts): 144B -> b64 writes & b128 reads bank-optimal
#define QSCALE 0.18033688011112042f   // 0.125 * log2(e); scores consumed by exp2

typedef __attribute__((ext_vector_type(8))) short bf16x8;
typedef __attribute__((ext_vector_type(4))) float floatx4;
typedef __attribute__((ext_vector_type(8))) unsigned short ushort8;

static __device__ __forceinline__ unsigned short f2bf(float f) {
  union { float f; unsigned int u; } v; v.f = f;
  return (unsigned short)((v.u + 0x7FFFu + ((v.u >> 16) & 1u)) >> 16);
}

static __device__ __forceinline__ void lds16(const void* g, void* l) {
  __builtin_amdgcn_global_load_lds(
      (const __attribute__((address_space(1))) unsigned int*)g,
      (__attribute__((address_space(3))) unsigned int*)l, 16, 0, 0);
}

// ---------------- fused cast f32 -> bf16 (all 7 tensors, one launch) ----------
__global__ __launch_bounds__(256) void cast_all(
    const float* __restrict__ xq, const float* __restrict__ xk,
    const float* __restrict__ xv, const float* __restrict__ wq,
    const float* __restrict__ wk, const float* __restrict__ wv,
    const float* __restrict__ wp,
    unsigned short* __restrict__ Xq, unsigned short* __restrict__ Xk,
    unsigned short* __restrict__ Xv, unsigned short* __restrict__ Wq,
    unsigned short* __restrict__ Wk, unsigned short* __restrict__ Wv,
    unsigned short* __restrict__ Wp) {
  int i = blockIdx.x * 256 + threadIdx.x;
  const float* s; unsigned short* d; int off;
  if (i < 3 * X8) {
    int t = i / X8; off = i - t * X8;
    s = (t == 0) ? xq : (t == 1) ? xk : xv;
    d = (t == 0) ? Xq : (t == 1) ? Xk : Xv;
  } else {
    int j = i - 3 * X8; int t = j / W8; off = j - t * W8;
    s = (t == 0) ? wq : (t == 1) ? wk : (t == 2) ? wv : wp;
    d = (t == 0) ? Wq : (t == 1) ? Wk : (t == 2) ? Wv : Wp;
  }
  const float4* sp = (const float4*)s + (size_t)off * 2;
  float4 a = sp[0], b = sp[1];
  ushort8 o;
  o[0] = f2bf(a.x); o[1] = f2bf(a.y); o[2] = f2bf(a.z); o[3] = f2bf(a.w);
  o[4] = f2bf(b.x); o[5] = f2bf(b.y); o[6] = f2bf(b.z); o[7] = f2bf(b.w);
  *(ushort8*)(d + (size_t)off * 8) = o;
}

// ---------------- fused QKV NT-GEMM (128x128 tiles, swizzled LDS) ----------
// z=0: Q = Xq Wq^T * QSCALE -> [B,H,N,D]; z=1: K -> [B,H,N,D];
// z=2: V^T = Wv Xv^T -> Vt [B,H,D,N] (coalesced writes).
__global__ __launch_bounds__(256) void gemm_qkv(
    const unsigned short* __restrict__ Xq, const unsigned short* __restrict__ Xk,
    const unsigned short* __restrict__ Xv, const unsigned short* __restrict__ Wq,
    const unsigned short* __restrict__ Wk, const unsigned short* __restrict__ Wv,
    unsigned short* __restrict__ Qo, unsigned short* __restrict__ Ko,
    unsigned short* __restrict__ Vo) {
  int z = blockIdx.z;
  const unsigned short* A; const unsigned short* B; int m0, n0;
  if (z == 0)      { A = Xq; B = Wq; m0 = blockIdx.y * 128; n0 = blockIdx.x * 128; }
  else if (z == 1) { A = Xk; B = Wk; m0 = blockIdx.y * 128; n0 = blockIdx.x * 128; }
  else             { A = Wv; B = Xv; m0 = blockIdx.x * 128; n0 = blockIdx.y * 128; }
  __shared__ __align__(16) unsigned short As[128 * 64];
  __shared__ __align__(16) unsigned short Bs[128 * 64];
  int tid = threadIdx.x, lane = tid & 63, wave = tid >> 6;
  int quad = lane >> 4, l15 = lane & 15, l7 = l15 & 7;
  int wm = (wave >> 1) * 64, wn = (wave & 1) * 64;
  floatx4 acc[4][4];
#pragma unroll
  for (int i = 0; i < 4; i++)
#pragma unroll
    for (int j = 0; j < 4; j++) acc[i][j] = (floatx4){0.f, 0.f, 0.f, 0.f};

  for (int k0 = 0; k0 < CDIM; k0 += 64) {
#pragma unroll
    for (int i = 0; i < 4; i++) {
      int idx = i * 256 + tid;
      int R = idx >> 3, c = (idx & 7) ^ (R & 7);
      lds16(A + (size_t)(m0 + R) * CDIM + k0 + c * 8, &As[idx * 8]);
      lds16(B + (size_t)(n0 + R) * CDIM + k0 + c * 8, &Bs[idx * 8]);
    }
    __syncthreads();
#pragma unroll
    for (int ks = 0; ks < 2; ks++) {
      int csw = ((ks * 4 + quad) ^ l7) * 8;
      bf16x8 af[4], bfr[4];
#pragma unroll
      for (int i = 0; i < 4; i++)
        af[i] = *(const bf16x8*)&As[(wm + i * 16 + l15) * 64 + csw];
#pragma unroll
      for (int i = 0; i < 4; i++)
        bfr[i] = *(const bf16x8*)&Bs[(wn + i * 16 + l15) * 64 + csw];
#pragma unroll
      for (int mi = 0; mi < 4; mi++)
#pragma unroll
        for (int ni = 0; ni < 4; ni++)
          acc[mi][ni] = __builtin_amdgcn_mfma_f32_16x16x32_bf16(
              af[mi], bfr[ni], acc[mi][ni], 0, 0, 0);
    }
    __syncthreads();
  }
#pragma unroll
  for (int mi = 0; mi < 4; mi++) {
#pragma unroll
    for (int ni = 0; ni < 4; ni++) {
#pragma unroll
      for (int r = 0; r < 4; r++) {
        int grow = m0 + wm + mi * 16 + quad * 4 + r;
        int gcol = n0 + wn + ni * 16 + l15;
        float v = acc[mi][ni][r];
        if (z == 0) {
          int b = grow >> 11, nq = grow & 2047, h = gcol >> 6, d = gcol & 63;
          Qo[((size_t)(b * NH + h) * NSEQ + nq) * HD + d] = f2bf(v * QSCALE);
        } else if (z == 1) {
          int b = grow >> 11, nq = grow & 2047, h = gcol >> 6, d = gcol & 63;
          Ko[((size_t)(b * NH + h) * NSEQ + nq) * HD + d] = f2bf(v);
        } else {
          int b = gcol >> 11, nq = gcol & 2047;
          Vo[((size_t)b * CDIM + grow) * NSEQ + nq] = f2bf(v);
        }
      }
    }
  }
}

// ---------------- flash attention: S^T = K Q^T formulation ----------------
// Q,K: [24][2048][64] bf16 (Q pre-scaled); Vt: [24][64][2048] bf16.
// ctx: [4096][768] bf16. grid=(32,24), 256 thr = 4 waves x 16 q-rows.
// S^T C-layout: row=kv=quad*4+r, col=q=l15 -> lane holds 4 consecutive kv for
// its q => P[q][kv] written as packed b64; per-lane scalar l; O^T=Vt*P^T gives
// row=d, col=q -> packed b64 ctx stores.
__global__ __launch_bounds__(256) void attn_kernel(
    const unsigned short* __restrict__ Q, const unsigned short* __restrict__ K,
    const unsigned short* __restrict__ Vt, unsigned short* __restrict__ ctx) {
  int qt = blockIdx.x, bh = blockIdx.y;
  int tid = threadIdx.x, lane = tid & 63, wave = tid >> 6;
  int quad = lane >> 4, l15 = lane & 15, l7 = l15 & 7;
  __shared__ __align__(16) unsigned short Ks[64 * 64];
  __shared__ __align__(16) unsigned short Vs[64 * 64];
  __shared__ __align__(16) unsigned short Ps[4][16 * PSTR];

  const unsigned short* Qg = Q + ((size_t)bh * NSEQ + qt * 64 + wave * 16) * HD;
  const unsigned short* Kg = K + (size_t)bh * NSEQ * HD;
  const unsigned short* Vg = Vt + (size_t)bh * HD * NSEQ;

  // Q fragments in registers (B-operand: n=q=l15, k=d=ks*32+quad*8..)
  bf16x8 qf[2];
#pragma unroll
  for (int ks = 0; ks < 2; ks++)
    qf[ks] = *(const bf16x8*)(Qg + l15 * HD + ks * 32 + quad * 8);

  // staging offsets: 512 chunks per tile, 2 per thread
  int kgo[2], vgo[2], ldst[2];
#pragma unroll
  for (int i = 0; i < 2; i++) {
    int idx = i * 256 + tid;
    int R = idx >> 3, c = (idx & 7) ^ (R & 7);
    kgo[i] = R * HD + c * 8;
    vgo[i] = R * NSEQ + c * 8;
    ldst[i] = idx * 8;
  }
  unsigned short* Pw = &Ps[wave][0];

  float lacc = 0.f;
  floatx4 o[4];
#pragma unroll
  for (int dt = 0; dt < 4; dt++) o[dt] = (floatx4){0.f, 0.f, 0.f, 0.f};

  for (int t = 0; t < 32; t++) {
    int k0 = t * 64;
#pragma unroll
    for (int i = 0; i < 2; i++) {
      lds16(Kg + (size_t)k0 * HD + kgo[i], &Ks[ldst[i]]);
      lds16(Vg + k0 + vgo[i], &Vs[ldst[i]]);
    }
    __syncthreads();
    // S^T = K Q^T: st[nt] rows kv=nt*16+quad*4+r, col q=l15
#pragma unroll
    for (int nt = 0; nt < 4; nt++) {
      bf16x8 kf0 = *(const bf16x8*)&Ks[(nt * 16 + l15) * 64 + ((quad) ^ l7) * 8];
      bf16x8 kf1 = *(const bf16x8*)&Ks[(nt * 16 + l15) * 64 + ((4 + quad) ^ l7) * 8];
      floatx4 st = (floatx4){0.f, 0.f, 0.f, 0.f};
      st = __builtin_amdgcn_mfma_f32_16x16x32_bf16(kf0, qf[0], st, 0, 0, 0);
      st = __builtin_amdgcn_mfma_f32_16x16x32_bf16(kf1, qf[1], st, 0, 0, 0);
      // p = exp2(s); pack 4 consecutive kv into one b64 write at P[q=l15][kv]
      float p0 = __builtin_exp2f(st[0]), p1 = __builtin_exp2f(st[1]);
      float p2 = __builtin_exp2f(st[2]), p3 = __builtin_exp2f(st[3]);
      lacc += (p0 + p1) + (p2 + p3);
      unsigned lo = (unsigned)f2bf(p0) | ((unsigned)f2bf(p1) << 16);
      unsigned hi = (unsigned)f2bf(p2) | ((unsigned)f2bf(p3) << 16);
      *(uint2*)&Pw[l15 * PSTR + nt * 16 + quad * 4] = make_uint2(lo, hi);
    }
    // O^T += Vt P^T: A=vf (m=d), B=pf (n=q) -> rows d, cols q
#pragma unroll
    for (int ks = 0; ks < 2; ks++) {
      bf16x8 pf = *(const bf16x8*)&Pw[l15 * PSTR + ks * 32 + quad * 8];
#pragma unroll
      for (int dt = 0; dt < 4; dt++) {
        bf16x8 vf = *(const bf16x8*)&Vs[(dt * 16 + l15) * 64 + ((ks * 4 + quad) ^ l7) * 8];
        o[dt] = __builtin_amdgcn_mfma_f32_16x16x32_bf16(vf, pf, o[dt], 0, 0, 0);
      }
    }
    __syncthreads();
  }
  // l[q]: sum partial lacc across the 4 quads holding the same q=l15
  lacc += __shfl_xor(lacc, 16, 64);
  lacc += __shfl_xor(lacc, 32, 64);
  float inv = 1.f / lacc;
  int b = bh / NH, h = bh - b * NH;
  int qrow = qt * 64 + wave * 16 + l15;
  size_t gbase = (size_t)(b * NSEQ + qrow) * CDIM + h * HD + quad * 4;
#pragma unroll
  for (int dt = 0; dt < 4; dt++) {
    float v0 = o[dt][0] * inv, v1 = o[dt][1] * inv;
    float v2 = o[dt][2] * inv, v3 = o[dt][3] * inv;
    unsigned lo = (unsigned)f2bf(v0) | ((unsigned)f2bf(v1) << 16);
    unsigned hi = (unsigned)f2bf(v2) | ((unsigned)f2bf(v3) << 16);
    *(uint2*)&ctx[gbase + dt * 16] = make_uint2(lo, hi);
  }
}

// ---------------- output NT-GEMM + bias, 64x64 tiles, f32 out ----------------
__global__ __launch_bounds__(256) void gemm_out(
    const unsigned short* __restrict__ A, const unsigned short* __restrict__ B,
    const float* __restrict__ bias, float* __restrict__ out) {
  int m0 = blockIdx.y * 64, n0 = blockIdx.x * 64;
  __shared__ __align__(16) unsigned short As[64 * 64];
  __shared__ __align__(16) unsigned short Bs[64 * 64];
  int tid = threadIdx.x, lane = tid & 63, wave = tid >> 6;
  int quad = lane >> 4, l15 = lane & 15, l7 = l15 & 7;
  int wm = (wave >> 1) * 32, wn = (wave & 1) * 32;
  floatx4 acc[2][2];
#pragma unroll
  for (int i = 0; i < 2; i++)
#pragma unroll
    for (int j = 0; j < 2; j++) acc[i][j] = (floatx4){0.f, 0.f, 0.f, 0.f};

  for (int k0 = 0; k0 < CDIM; k0 += 64) {
#pragma unroll
    for (int i = 0; i < 2; i++) {
      int idx = i * 256 + tid;
      int R = idx >> 3, c = (idx & 7) ^ (R & 7);
      lds16(A + (size_t)(m0 + R) * CDIM + k0 + c * 8, &As[idx * 8]);
      lds16(B + (size_t)(n0 + R) * CDIM + k0 + c * 8, &Bs[idx * 8]);
    }
    __syncthreads();
#pragma unroll
    for (int ks = 0; ks < 2; ks++) {
      int csw = ((ks * 4 + quad) ^ l7) * 8;
      bf16x8 af[2], bfr[2];
#pragma unroll
      for (int i = 0; i < 2; i++)
        af[i] = *(const bf16x8*)&As[(wm + i * 16 + l15) * 64 + csw];
#pragma unroll
      for (int i = 0; i < 2; i++)
        bfr[i] = *(const bf16x8*)&Bs[(wn + i * 16 + l15) * 64 + csw];
#pragma unroll
      for (int mi = 0; mi < 2; mi++)
#pragma unroll
        for (int ni = 0; ni < 2; ni++)
          acc[mi][ni] = __builtin_amdgcn_mfma_f32_16x16x32_bf16(
              af[mi], bfr[ni], acc[mi][ni], 0, 0, 0);
    }
    __syncthreads();
  }
  float bv[2];
#pragma unroll
  for (int ni = 0; ni < 2; ni++) bv[ni] = bias[n0 + wn + ni * 16 + l15];
#pragma unroll
  for (int mi = 0; mi < 2; mi++)
#pragma unroll
    for (int ni = 0; ni < 2; ni++)
#pragma unroll
      for (int r = 0; r < 4; r++) {
        int grow = m0 + wm + mi * 16 + quad * 4 + r;
        int gcol = n0 + wn + ni * 16 + l15;
        out[(size_t)grow * CDIM + gcol] = acc[mi][ni][r] + bv[ni];
      }
}

extern "C" void kernel_launch(void* const* d_in, const int* in_sizes, int n_in,
                              void* d_out, int out_size, void* d_ws, size_t ws_size,
                              hipStream_t stream) {
  const float* xq = (const float*)d_in[0];
  const float* xk = (const float*)d_in[1];
  const float* xv = (const float*)d_in[2];
  const float* wq = (const float*)d_in[3];
  const float* wk = (const float*)d_in[4];
  const float* wv = (const float*)d_in[5];
  const float* wp = (const float*)d_in[6];
  const float* bp = (const float*)d_in[7];
  float* out = (float*)d_out;

  char* p = (char*)d_ws;
  unsigned short* Xq = (unsigned short*)p; p += (size_t)XEL * 2;
  unsigned short* Xk = (unsigned short*)p; p += (size_t)XEL * 2;
  unsigned short* Xv = (unsigned short*)p; p += (size_t)XEL * 2;
  unsigned short* Wq = (unsigned short*)p; p += (size_t)WEL * 2;
  unsigned short* Wk = (unsigned short*)p; p += (size_t)WEL * 2;
  unsigned short* Wv = (unsigned short*)p; p += (size_t)WEL * 2;
  unsigned short* Wp = (unsigned short*)p; p += (size_t)WEL * 2;
  unsigned short* Qb = (unsigned short*)p; p += (size_t)XEL * 2;
  unsigned short* Kb = (unsigned short*)p; p += (size_t)XEL * 2;
  unsigned short* Vb = (unsigned short*)p; p += (size_t)XEL * 2;
  unsigned short* Cx = (unsigned short*)p; p += (size_t)XEL * 2;

  cast_all<<<(3 * X8 + 4 * W8) / 256, 256, 0, stream>>>(
      xq, xk, xv, wq, wk, wv, wp, Xq, Xk, Xv, Wq, Wk, Wv, Wp);

  gemm_qkv<<<dim3(CDIM / 128, MTOT / 128, 3), 256, 0, stream>>>(
      Xq, Xk, Xv, Wq, Wk, Wv, Qb, Kb, Vb);

  attn_kernel<<<dim3(NSEQ / 64, 2 * NH), 256, 0, stream>>>(Qb, Kb, Vb, Cx);

  gemm_out<<<dim3(CDIM / 64, MTOT / 64), 256, 0, stream>>>(Cx, Wp, bp, out);
}